// Round 1
// baseline (437.268 us; speedup 1.0000x reference)
//
#include <hip/hip_runtime.h>

#define S_LEN 2048
#define B_SZ 2048

typedef float v2 __attribute__((ext_vector_type(2)));
#define FMA2(a, b, c) __builtin_elementwise_fma((a), (b), (c))

// Pure-VALU DPP move. quad_perm (0x00-0xFF) and row_shr:N (0x110+N) patterns.
template <int CTRL>
__device__ __forceinline__ float dppmov(float v) {
  int r = __builtin_amdgcn_update_dpp(0, __builtin_bit_cast(int, v), CTRL, 0xF,
                                      0xF, true);
  return __builtin_bit_cast(float, r);
}

// R11: zero-LDS version. Decomposition unchanged (ONE wave = 4 batches x
// 4 layers x 4 hidden; lane = b*16 + l*4 + j; each lane computes all 4
// gates of hidden j). The layer handoff no longer goes through an LDS
// ring: layer l's lanes sit exactly 4 lanes above layer l-1's lanes in
// the same 16-lane DPP row, and each lane already holds all 4 rotations
// of its layer's h (hv01.x/.y, hv23.x/.y). Four row_shr:4 DPP moves at
// tick top deliver the below-layer h vector (j-rotated convention ->
// Wih weights for l>0 are pre-rotated by j exactly like Whh). bound_ctrl
// zeroes the l==0 lanes, which take x(t) instead (cndmask). Skew stays
// 2 ticks/layer: the shift captured at tick tau is consumed at tau+1
// (hin pattern), mirroring the old 1-tick LDS slack. x lives in a
// register ring xc0..xc7 (slot reloaded right after consumption -> 8
// ticks of vmcnt slack). y: lane (l=3,j=0) holds h0..h3 in natural
// order after the rotation update; per-tick predicated dword store (4
// consecutive dwords per wave). No __shared__, no DS ops, no barriers.
#define TICK(U)                                                                \
  {                                                                            \
    /* below-layer h from PREV tick's hv (read before hv update) */            \
    float s0 = dppmov<0x114>(hv01.x); /* row_shr:4 */                          \
    float s1 = dppmov<0x114>(hv01.y);                                          \
    float s2 = dppmov<0x114>(hv23.x);                                          \
    float s3 = dppmov<0x114>(hv23.y);                                          \
    v2 h01, h23;                                                               \
    h01.x = hx0;                                                               \
    h01.y = hx1;                                                               \
    h23.x = hx2;                                                               \
    h23.y = hx3;                                                               \
    v2 A0 = FMA2(wi01[0], h01, bias2[0]);                                      \
    v2 A1 = FMA2(wi01[1], h01, bias2[1]);                                      \
    v2 A2 = FMA2(wi01[2], h01, bias2[2]);                                      \
    v2 A3 = FMA2(wi01[3], h01, bias2[3]);                                      \
    A0 = FMA2(wi23[0], h23, A0);                                               \
    A1 = FMA2(wi23[1], h23, A1);                                               \
    A2 = FMA2(wi23[2], h23, A2);                                               \
    A3 = FMA2(wi23[3], h23, A3);                                               \
    A0 = FMA2(wh01[0], hv01, A0);                                              \
    A1 = FMA2(wh01[1], hv01, A1);                                              \
    A2 = FMA2(wh01[2], hv01, A2);                                              \
    A3 = FMA2(wh01[3], hv01, A3);                                              \
    A0 = FMA2(wh23[0], hv23, A0);                                              \
    A1 = FMA2(wh23[1], hv23, A1);                                              \
    A2 = FMA2(wh23[2], hv23, A2);                                              \
    A3 = FMA2(wh23[3], hv23, A3);                                              \
    float a0 = A0.x + A0.y, a1 = A1.x + A1.y;                                  \
    float a2 = A2.x + A2.y, a3 = A3.x + A3.y;                                  \
    float e0 = __builtin_amdgcn_exp2f(a0); /* gates pre-scaled by kk_t */      \
    float e1 = __builtin_amdgcn_exp2f(a1);                                     \
    float e2 = __builtin_amdgcn_exp2f(a2);                                     \
    float e3 = __builtin_amdgcn_exp2f(a3);                                     \
    float r0 = __builtin_amdgcn_rcpf(1.0f + e0); /* sigmoid(i) */              \
    float r1 = __builtin_amdgcn_rcpf(1.0f + e1); /* sigmoid(f) */              \
    float r2 = __builtin_amdgcn_rcpf(1.0f + e2); /* (tanh(g)+1)/2 */           \
    float r3 = __builtin_amdgcn_rcpf(1.0f + e3); /* sigmoid(o) */              \
    float gi = KT * r0;                          /* KT fold: cKT = KT*c */     \
    float gg = fmaf(2.0f, r2, -1.0f);            /* tanh(g) */                 \
    cKT = fmaf(r1, cKT, gi * gg);                                              \
    float te = __builtin_amdgcn_exp2f(cKT);                                    \
    float tr = __builtin_amdgcn_rcpf(1.0f + te);                               \
    float go2 = r3 + r3;                                                       \
    float hh = fmaf(go2, tr, -r3); /* = o * tanh(c) */                         \
    hv01.x = hh;                                                               \
    hv01.y = dppmov<0x39>(hh); /* h_{(j+1)&3} */                               \
    hv23.x = dppmov<0x4E>(hh); /* h_{(j+2)&3} */                               \
    hv23.y = dppmov<0x93>(hh); /* h_{(j+3)&3} */                               \
    /* next-tick input: x for layer-0 lanes, shifted h for l>0        */       \
    /* (row_shr bound_ctrl already zeroed s2/s3 on l==0 lanes)        */       \
    hx0 = lz ? xc##U.x : s0;                                                   \
    hx1 = lz ? xc##U.y : s1;                                                   \
    hx2 = s2;                                                                  \
    hx3 = s3;                                                                  \
    /* y for t = tau-6 from fresh layer-3 h (natural order on j==0) */         \
    float yv = fmaf(wo3, hv23.y,                                               \
                    fmaf(wo2, hv23.x, fmaf(wo1, hv01.y, fmaf(wo0, hv01.x,      \
                                                             bo))));           \
    if (yl && (unsigned)ty < (unsigned)S_LEN) outp[yi] = yv;                   \
    ty += 1;                                                                   \
    yi += B_SZ;                                                                \
  }

// warm-up reset: layer l is live from tau = 2l
#define RESET(U)                                                               \
  if (2 * l > (U)) {                                                           \
    cKT = 0.0f;                                                                \
    hv01.x = 0.0f;                                                             \
    hv01.y = 0.0f;                                                             \
    hv23.x = 0.0f;                                                             \
    hv23.y = 0.0f;                                                             \
  }

// reload slot U (just consumed by TICK(U)) with x for the next epoch:
// slot U at epoch k holds x(8k+U+1)  ->  reload t = 8(k+1)+U+1 = TB+U
#define XLOAD(U, TB)                                                           \
  {                                                                            \
    int t_ = (TB) + (U);                                                       \
    if (t_ >= S_LEN) t_ = S_LEN - 1; /* drain clamp (stores masked) */         \
    xc##U = px[(size_t)t_ * B_SZ + bidx];                                      \
  }

__global__ void __launch_bounds__(64, 1)
    lstm_kernel(const float *__restrict__ x, const float *__restrict__ Wih0,
                const float *__restrict__ Whh0, const float *__restrict__ bih0,
                const float *__restrict__ bhh0, const float *__restrict__ Wihr,
                const float *__restrict__ Whhr, const float *__restrict__ bihr,
                const float *__restrict__ bhhr, const float *__restrict__ Wout,
                const float *__restrict__ bout, float *__restrict__ out) {
  const int lane = threadIdx.x & 63;
  const int b = lane >> 4;       // batch slot
  const int l = (lane >> 2) & 3; // layer
  const int j = lane & 3;        // hidden unit
  const int bidx = blockIdx.x * 4 + b;
  const bool lz = (l == 0);
  const bool yl = (l == 3) && (j == 0);

  const float L2E = 1.4426950408889634f;
  const float KT = -2.8853900817779268f; // -2*log2(e)
  const float kks[4] = {-L2E, -L2E, -2.0f * L2E, -L2E};

  // ---- per-lane weights: all 4 gates of hidden j, layer l; pk-paired,
  //      pre-scaled by kk_t; BOTH wh and (for l>0) wi pre-rotated by j
  //      (wi[k] ~ Wih[row][(j+k)&3]) to match the rotated h convention
  //      delivered by the row_shr:4 handoff. Layer 0 keeps natural wi
  //      order since its input (x0,x1,0,0) is lane-uniform per batch. ----
  v2 wi01[4], wi23[4], wh01[4], wh23[4], bias2[4];
#pragma unroll
  for (int t = 0; t < 4; ++t) {
    const int row = t * 4 + j;
    const float kk = kks[t];
    float i0, i1, i2, i3, w0, w1, w2, w3, bs;
    if (l == 0) {
      i0 = Wih0[row * 2 + 0];
      i1 = Wih0[row * 2 + 1];
      i2 = 0.0f;
      i3 = 0.0f;
      w0 = Whh0[row * 4 + j];
      w1 = Whh0[row * 4 + ((j + 1) & 3)];
      w2 = Whh0[row * 4 + ((j + 2) & 3)];
      w3 = Whh0[row * 4 + ((j + 3) & 3)];
      bs = bih0[row] + bhh0[row];
    } else {
      const int m = l - 1;
      i0 = Wihr[m * 64 + row * 4 + j];
      i1 = Wihr[m * 64 + row * 4 + ((j + 1) & 3)];
      i2 = Wihr[m * 64 + row * 4 + ((j + 2) & 3)];
      i3 = Wihr[m * 64 + row * 4 + ((j + 3) & 3)];
      w0 = Whhr[m * 64 + row * 4 + j];
      w1 = Whhr[m * 64 + row * 4 + ((j + 1) & 3)];
      w2 = Whhr[m * 64 + row * 4 + ((j + 2) & 3)];
      w3 = Whhr[m * 64 + row * 4 + ((j + 3) & 3)];
      bs = bihr[m * 16 + row] + bhhr[m * 16 + row];
    }
    wi01[t].x = kk * i0;
    wi01[t].y = kk * i1;
    wi23[t].x = kk * i2;
    wi23[t].y = kk * i3;
    wh01[t].x = kk * w0;
    wh01[t].y = kk * w1;
    wh23[t].x = kk * w2;
    wh23[t].y = kk * w3;
    bias2[t].x = kk * bs;
    bias2[t].y = 0.0f;
  }
  const float wo0 = Wout[0], wo1 = Wout[1], wo2 = Wout[2], wo3 = Wout[3];
  const float bo = bout[0];

  const float2 *__restrict__ px = (const float2 *)x;
  float *__restrict__ outp = out;

  // ---- state ----
  v2 hv01, hv23;
  hv01.x = 0.0f;
  hv01.y = 0.0f;
  hv23.x = 0.0f;
  hv23.y = 0.0f;
  float cKT = 0.0f;
  float hx0, hx1, hx2, hx3; // hin: input vector for THIS tick

  // initial hin (tick 0): layer-0 lanes get x(0), others 0
  {
    float2 x00 = px[bidx];
    hx0 = lz ? x00.x : 0.0f;
    hx1 = lz ? x00.y : 0.0f;
    hx2 = 0.0f;
    hx3 = 0.0f;
  }

  // prime x ring: slot U holds x(U+1) for epoch 0 (consumed at tick U,
  // becomes hin at tick U+1)
  float2 xc0 = px[1 * B_SZ + bidx];
  float2 xc1 = px[2 * B_SZ + bidx];
  float2 xc2 = px[3 * B_SZ + bidx];
  float2 xc3 = px[4 * B_SZ + bidx];
  float2 xc4 = px[5 * B_SZ + bidx];
  float2 xc5 = px[6 * B_SZ + bidx];
  float2 xc6 = px[7 * B_SZ + bidx];
  float2 xc7 = px[8 * B_SZ + bidx];

  int ty = -6;               // y time index (layer 3 skew = 6 ticks)
  int yi = -6 * B_SZ + bidx; // y store element index

  // ---- epoch 0 (peeled: warm-up resets at u=0..5) ----
  TICK(0); RESET(0); XLOAD(0, 9);
  TICK(1); RESET(1); XLOAD(1, 9);
  TICK(2); RESET(2); XLOAD(2, 9);
  TICK(3); RESET(3); XLOAD(3, 9);
  TICK(4); RESET(4); XLOAD(4, 9);
  TICK(5); RESET(5); XLOAD(5, 9);
  TICK(6); XLOAD(6, 9);
  TICK(7); XLOAD(7, 9);

  // ---- epochs 1..256: ticks tau = 8k..8k+7 ----
#pragma unroll 1
  for (int k = 1; k < 257; ++k) {
    const int tb = 8 * k + 9;
    TICK(0); XLOAD(0, tb);
    TICK(1); XLOAD(1, tb);
    TICK(2); XLOAD(2, tb);
    TICK(3); XLOAD(3, tb);
    TICK(4); XLOAD(4, tb);
    TICK(5); XLOAD(5, tb);
    TICK(6); XLOAD(6, tb);
    TICK(7); XLOAD(7, tb);
  }
}

extern "C" void kernel_launch(void *const *d_in, const int *in_sizes, int n_in,
                              void *d_out, int out_size, void *d_ws,
                              size_t ws_size, hipStream_t stream) {
  (void)in_sizes;
  (void)n_in;
  (void)out_size;
  (void)d_ws;
  (void)ws_size;
  const float *x = (const float *)d_in[0];
  const float *Wih0 = (const float *)d_in[1];
  const float *Whh0 = (const float *)d_in[2];
  const float *bih0 = (const float *)d_in[3];
  const float *bhh0 = (const float *)d_in[4];
  const float *Wihr = (const float *)d_in[5];
  const float *Whhr = (const float *)d_in[6];
  const float *bihr = (const float *)d_in[7];
  const float *bhhr = (const float *)d_in[8];
  const float *Wout = (const float *)d_in[9];
  const float *bout = (const float *)d_in[10];
  lstm_kernel<<<dim3(B_SZ / 4), dim3(64), 0, stream>>>(
      x, Wih0, Whh0, bih0, bhh0, Wihr, Whhr, bihr, bhhr, Wout, bout,
      (float *)d_out);
}

// Round 2
// 366.447 us; speedup vs baseline: 1.1933x; 1.1933x over previous
//
#include <hip/hip_runtime.h>

#define S_LEN 2048
#define B_SZ 2048

typedef float v2 __attribute__((ext_vector_type(2)));
#define FMA2(a, b, c) __builtin_elementwise_fma((a), (b), (c))

// Pure-VALU DPP move (quad_perm patterns; old=0, bound_ctrl=1).
template <int CTRL>
__device__ __forceinline__ float dppmov(float v) {
  int r = __builtin_amdgcn_update_dpp(0, __builtin_bit_cast(int, v), CTRL, 0xF,
                                      0xF, true);
  return __builtin_bit_cast(float, r);
}

// DPP with explicit old operand: invalid lanes (bound_ctrl=0) keep `old`.
// row_shr:4 invalid lanes are exactly the l==0 lanes -> x rides in `old`.
template <int CTRL, bool BC>
__device__ __forceinline__ float dppold(float old, float v) {
  int r = __builtin_amdgcn_update_dpp(__builtin_bit_cast(int, old),
                                      __builtin_bit_cast(int, v), CTRL, 0xF,
                                      0xF, BC);
  return __builtin_bit_cast(float, r);
}

// R12: zero-LDS + per-epoch-amortized VMEM. Decomposition unchanged
// (wave = 4 batches x 4 layers x 4 hidden; lane = b*16 + l*4 + j; each
// lane computes all 4 gates of hidden j). Layer handoff = 4 row_shr:4
// DPPs/tick reading PREV tick's hv (lag-2 skew preserved: value captured
// at tick tau is consumed at tau+1). x is folded into the handoff DPP's
// `old` operand (bound_ctrl=0) -> zero cndmasks. y accumulated per tick
// as 2 pk_fma into per-slot v2 regs; horizontal add + 8 predicated
// stores once per epoch. x register ring xc0..xc7 reloaded one slot per
// tick via an advancing per-epoch pointer (8-tick vmcnt slack). No
// per-tick branches, no per-tick scalar index math, no LDS, no barriers.
#define TICK(U)                                                                \
  {                                                                            \
    /* next-tick input: shifted PREV-tick hv; l0 lanes keep xc (old) */        \
    float ns0 = dppold<0x114, false>(xc##U.x, hv01.x); /* row_shr:4 */         \
    float ns1 = dppold<0x114, false>(xc##U.y, hv01.y);                         \
    float ns2 = dppold<0x114, true>(0.0f, hv23.x);                             \
    float ns3 = dppold<0x114, true>(0.0f, hv23.y);                             \
    v2 h01, h23;                                                               \
    h01.x = hx0;                                                               \
    h01.y = hx1;                                                               \
    h23.x = hx2;                                                               \
    h23.y = hx3;                                                               \
    v2 A0 = FMA2(wi01[0], h01, bias2[0]);                                      \
    v2 A1 = FMA2(wi01[1], h01, bias2[1]);                                      \
    v2 A2 = FMA2(wi01[2], h01, bias2[2]);                                      \
    v2 A3 = FMA2(wi01[3], h01, bias2[3]);                                      \
    A0 = FMA2(wi23[0], h23, A0);                                               \
    A1 = FMA2(wi23[1], h23, A1);                                               \
    A2 = FMA2(wi23[2], h23, A2);                                               \
    A3 = FMA2(wi23[3], h23, A3);                                               \
    A0 = FMA2(wh01[0], hv01, A0);                                              \
    A1 = FMA2(wh01[1], hv01, A1);                                              \
    A2 = FMA2(wh01[2], hv01, A2);                                              \
    A3 = FMA2(wh01[3], hv01, A3);                                              \
    A0 = FMA2(wh23[0], hv23, A0);                                              \
    A1 = FMA2(wh23[1], hv23, A1);                                              \
    A2 = FMA2(wh23[2], hv23, A2);                                              \
    A3 = FMA2(wh23[3], hv23, A3);                                              \
    float a0 = A0.x + A0.y, a1 = A1.x + A1.y;                                  \
    float a2 = A2.x + A2.y, a3 = A3.x + A3.y;                                  \
    float e0 = __builtin_amdgcn_exp2f(a0); /* gates pre-scaled by kk_t */      \
    float e1 = __builtin_amdgcn_exp2f(a1);                                     \
    float e2 = __builtin_amdgcn_exp2f(a2);                                     \
    float e3 = __builtin_amdgcn_exp2f(a3);                                     \
    float r0 = __builtin_amdgcn_rcpf(1.0f + e0); /* sigmoid(i) */              \
    float r1 = __builtin_amdgcn_rcpf(1.0f + e1); /* sigmoid(f) */              \
    float r2 = __builtin_amdgcn_rcpf(1.0f + e2); /* (tanh(g)+1)/2 */           \
    float r3 = __builtin_amdgcn_rcpf(1.0f + e3); /* sigmoid(o) */              \
    float gi = KT * r0;                          /* KT fold: cKT = KT*c */     \
    float gg = fmaf(2.0f, r2, -1.0f);            /* tanh(g) */                 \
    cKT = fmaf(r1, cKT, gi * gg);                                              \
    float te = __builtin_amdgcn_exp2f(cKT);                                    \
    float tr = __builtin_amdgcn_rcpf(1.0f + te);                               \
    float go2 = r3 + r3;                                                       \
    float hh = fmaf(go2, tr, -r3); /* = o * tanh(c) */                         \
    hv01.x = hh;                                                               \
    hv01.y = dppmov<0x39>(hh); /* h_{(j+1)&3} */                               \
    hv23.x = dppmov<0x4E>(hh); /* h_{(j+2)&3} */                               \
    hv23.y = dppmov<0x93>(hh); /* h_{(j+3)&3} */                               \
    /* y slot: partial dot (horizontal add deferred to epoch store) */         \
    y##U = FMA2(wo01v, hv01, bo2);                                             \
    y##U = FMA2(wo23v, hv23, y##U);                                            \
    hx0 = ns0;                                                                 \
    hx1 = ns1;                                                                 \
    hx2 = ns2;                                                                 \
    hx3 = ns3;                                                                 \
  }

// warm-up reset: layer l is live from tau = 2l
#define RESET(U)                                                               \
  if (2 * l > (U)) {                                                           \
    cKT = 0.0f;                                                                \
    hv01.x = 0.0f;                                                             \
    hv01.y = 0.0f;                                                             \
    hv23.x = 0.0f;                                                             \
    hv23.y = 0.0f;                                                             \
  }

// reload slot U (just consumed) with its value for the NEXT epoch:
// epoch k's pointer pxk = px + (8k+9)*B_SZ + bidx -> slot U := x(8k+9+U)
#define XLOAD(U) xc##U = pxk[(U)*B_SZ];
#define XLOAD7C xc7 = pxk[6 * B_SZ]; /* tail clamp: x(2047) dup */

#define YST(U) ypk[(U)*B_SZ] = y##U.x + y##U.y;

__global__ void __launch_bounds__(64, 1)
    lstm_kernel(const float *__restrict__ x, const float *__restrict__ Wih0,
                const float *__restrict__ Whh0, const float *__restrict__ bih0,
                const float *__restrict__ bhh0, const float *__restrict__ Wihr,
                const float *__restrict__ Whhr, const float *__restrict__ bihr,
                const float *__restrict__ bhhr, const float *__restrict__ Wout,
                const float *__restrict__ bout, float *__restrict__ out) {
  const int lane = threadIdx.x & 63;
  const int b = lane >> 4;       // batch slot
  const int l = (lane >> 2) & 3; // layer
  const int j = lane & 3;        // hidden unit
  const int bidx = blockIdx.x * 4 + b;
  const bool lz = (l == 0);
  const bool yl = (l == 3) && (j == 0);

  const float L2E = 1.4426950408889634f;
  const float KT = -2.8853900817779268f; // -2*log2(e)
  const float kks[4] = {-L2E, -L2E, -2.0f * L2E, -L2E};

  // ---- per-lane weights: all 4 gates of hidden j, layer l; pk-paired,
  //      pre-scaled by kk_t; wh AND (l>0) wi pre-rotated by j to match
  //      the rotated h convention of the row_shr:4 handoff. ----
  v2 wi01[4], wi23[4], wh01[4], wh23[4], bias2[4];
#pragma unroll
  for (int t = 0; t < 4; ++t) {
    const int row = t * 4 + j;
    const float kk = kks[t];
    float i0, i1, i2, i3, w0, w1, w2, w3, bs;
    if (l == 0) {
      i0 = Wih0[row * 2 + 0];
      i1 = Wih0[row * 2 + 1];
      i2 = 0.0f;
      i3 = 0.0f;
      w0 = Whh0[row * 4 + j];
      w1 = Whh0[row * 4 + ((j + 1) & 3)];
      w2 = Whh0[row * 4 + ((j + 2) & 3)];
      w3 = Whh0[row * 4 + ((j + 3) & 3)];
      bs = bih0[row] + bhh0[row];
    } else {
      const int m = l - 1;
      i0 = Wihr[m * 64 + row * 4 + j];
      i1 = Wihr[m * 64 + row * 4 + ((j + 1) & 3)];
      i2 = Wihr[m * 64 + row * 4 + ((j + 2) & 3)];
      i3 = Wihr[m * 64 + row * 4 + ((j + 3) & 3)];
      w0 = Whhr[m * 64 + row * 4 + j];
      w1 = Whhr[m * 64 + row * 4 + ((j + 1) & 3)];
      w2 = Whhr[m * 64 + row * 4 + ((j + 2) & 3)];
      w3 = Whhr[m * 64 + row * 4 + ((j + 3) & 3)];
      bs = bihr[m * 16 + row] + bhhr[m * 16 + row];
    }
    wi01[t].x = kk * i0;
    wi01[t].y = kk * i1;
    wi23[t].x = kk * i2;
    wi23[t].y = kk * i3;
    wh01[t].x = kk * w0;
    wh01[t].y = kk * w1;
    wh23[t].x = kk * w2;
    wh23[t].y = kk * w3;
    bias2[t].x = kk * bs;
    bias2[t].y = 0.0f;
  }
  v2 wo01v, wo23v, bo2;
  wo01v.x = Wout[0];
  wo01v.y = Wout[1];
  wo23v.x = Wout[2];
  wo23v.y = Wout[3];
  bo2.x = bout[0];
  bo2.y = 0.0f;

  const float2 *__restrict__ px = (const float2 *)x;

  // ---- state ----
  v2 hv01, hv23;
  hv01.x = 0.0f;
  hv01.y = 0.0f;
  hv23.x = 0.0f;
  hv23.y = 0.0f;
  float cKT = 0.0f;
  float hx0, hx1, hx2, hx3; // input vector for THIS tick
  v2 y0, y1, y2, y3, y4, y5, y6, y7;

  // initial hin (tick 0): layer-0 lanes get x(0), others 0
  {
    float2 x00 = px[bidx];
    hx0 = lz ? x00.x : 0.0f;
    hx1 = lz ? x00.y : 0.0f;
    hx2 = 0.0f;
    hx3 = 0.0f;
  }

  // prime x ring: slot U holds x(U+1) for epoch 0 (folded into TICK(U)'s
  // handoff DPP as the input of tick U+1)
  float2 xc0 = px[1 * B_SZ + bidx];
  float2 xc1 = px[2 * B_SZ + bidx];
  float2 xc2 = px[3 * B_SZ + bidx];
  float2 xc3 = px[4 * B_SZ + bidx];
  float2 xc4 = px[5 * B_SZ + bidx];
  float2 xc5 = px[6 * B_SZ + bidx];
  float2 xc6 = px[7 * B_SZ + bidx];
  float2 xc7 = px[8 * B_SZ + bidx];

  // epoch-k reload pointer (epoch k loads slot U := x(8k+9+U))
  const float2 *__restrict__ pxk = px + 9 * B_SZ + bidx;
  // epoch-k y pointer (epoch k stores t = 8k-6+U); set after epoch 0
  float *__restrict__ ypk;

  // ---- epoch 0 (peeled: warm-up resets; stores only t=0,1) ----
  TICK(0); RESET(0); XLOAD(0);
  TICK(1); RESET(1); XLOAD(1);
  TICK(2); RESET(2); XLOAD(2);
  TICK(3); RESET(3); XLOAD(3);
  TICK(4); RESET(4); XLOAD(4);
  TICK(5); RESET(5); XLOAD(5);
  TICK(6); XLOAD(6);
  TICK(7); XLOAD(7);
  if (yl) {
    out[bidx] = y6.x + y6.y;         // t = 0
    out[B_SZ + bidx] = y7.x + y7.y;  // t = 1
  }
  pxk += 8 * B_SZ;
  ypk = out + 2 * B_SZ + bidx;

  // ---- main epochs k = 1..253 (all loads & stores in-bounds) ----
#pragma unroll 1
  for (int k = 1; k < 254; ++k) {
    TICK(0); XLOAD(0);
    TICK(1); XLOAD(1);
    TICK(2); XLOAD(2);
    TICK(3); XLOAD(3);
    TICK(4); XLOAD(4);
    TICK(5); XLOAD(5);
    TICK(6); XLOAD(6);
    TICK(7); XLOAD(7);
    if (yl) {
      YST(0); YST(1); YST(2); YST(3); YST(4); YST(5); YST(6); YST(7);
    }
    pxk += 8 * B_SZ;
    ypk += 8 * B_SZ;
  }

  // ---- epoch 254: last slot's reload would be x(2048) -> clamp ----
  TICK(0); XLOAD(0);
  TICK(1); XLOAD(1);
  TICK(2); XLOAD(2);
  TICK(3); XLOAD(3);
  TICK(4); XLOAD(4);
  TICK(5); XLOAD(5);
  TICK(6); XLOAD(6);
  TICK(7); XLOAD7C;
  if (yl) {
    YST(0); YST(1); YST(2); YST(3); YST(4); YST(5); YST(6); YST(7);
  }
  ypk += 8 * B_SZ;

  // ---- epoch 255: consumes last real x values; no reloads ----
  TICK(0);
  TICK(1);
  TICK(2);
  TICK(3);
  TICK(4);
  TICK(5);
  TICK(6);
  TICK(7);
  if (yl) {
    YST(0); YST(1); YST(2); YST(3); YST(4); YST(5); YST(6); YST(7);
  }
  ypk += 8 * B_SZ;

  // ---- epoch 256 (drain): 6 ticks, stores t = 2042..2047 ----
  TICK(0);
  TICK(1);
  TICK(2);
  TICK(3);
  TICK(4);
  TICK(5);
  if (yl) {
    YST(0); YST(1); YST(2); YST(3); YST(4); YST(5);
  }
}

extern "C" void kernel_launch(void *const *d_in, const int *in_sizes, int n_in,
                              void *d_out, int out_size, void *d_ws,
                              size_t ws_size, hipStream_t stream) {
  (void)in_sizes;
  (void)n_in;
  (void)out_size;
  (void)d_ws;
  (void)ws_size;
  const float *x = (const float *)d_in[0];
  const float *Wih0 = (const float *)d_in[1];
  const float *Whh0 = (const float *)d_in[2];
  const float *bih0 = (const float *)d_in[3];
  const float *bhh0 = (const float *)d_in[4];
  const float *Wihr = (const float *)d_in[5];
  const float *Whhr = (const float *)d_in[6];
  const float *bihr = (const float *)d_in[7];
  const float *bhhr = (const float *)d_in[8];
  const float *Wout = (const float *)d_in[9];
  const float *bout = (const float *)d_in[10];
  lstm_kernel<<<dim3(B_SZ / 4), dim3(64), 0, stream>>>(
      x, Wih0, Whh0, bih0, bhh0, Wihr, Whhr, bihr, bhhr, Wout, bout,
      (float *)d_out);
}